// Round 1
// baseline (3521.093 us; speedup 1.0000x reference)
//
#include <hip/hip_runtime.h>
#include <hip/hip_bf16.h>

static constexpr int VN = 500000;   // nodes
static constexpr int DD = 128;      // feature dim
static constexpr int NE = 1000000;  // hyperedges
static constexpr int KE = 8;        // nodes per hyperedge
static constexpr int CC = 16;       // layer-3 width
static constexpr int H1 = 8;        // hidden width
static constexpr int RS = 16;       // row stride for A/B scratch

// deg[v] = 1.0 (identity contribution)
__global__ __launch_bounds__(256) void k_init_deg(float* __restrict__ deg) {
    int i = blockIdx.x * 256 + threadIdx.x;
    if (i < VN) deg[i] = 1.0f;
}

// Fused: proj[v] = X[v,:]·rv ; A[v,0:8] = X[v,:]·W1  (one pass over X)
__global__ __launch_bounds__(256) void k_row(const float* __restrict__ X,
                                             const float* __restrict__ rv,
                                             const float* __restrict__ W1,
                                             float* __restrict__ proj,
                                             float* __restrict__ A) {
    int v = blockIdx.x * 256 + threadIdx.x;
    if (v >= VN) return;
    const float4* xr = reinterpret_cast<const float4*>(X + (size_t)v * DD);
    const float4* rr = reinterpret_cast<const float4*>(rv);
    float accP = 0.f;
    float accM[H1];
#pragma unroll
    for (int j = 0; j < H1; ++j) accM[j] = 0.f;
#pragma unroll 8
    for (int k = 0; k < DD / 4; ++k) {
        float4 x = xr[k];
        float4 r = rr[k];
        accP += x.x * r.x + x.y * r.y + x.z * r.z + x.w * r.w;
#pragma unroll
        for (int q = 0; q < 4; ++q) {
            float xv = (q == 0) ? x.x : (q == 1) ? x.y : (q == 2) ? x.z : x.w;
            const float4 wa = *reinterpret_cast<const float4*>(W1 + (size_t)(k * 4 + q) * H1);
            const float4 wb = *reinterpret_cast<const float4*>(W1 + (size_t)(k * 4 + q) * H1 + 4);
            accM[0] += xv * wa.x; accM[1] += xv * wa.y;
            accM[2] += xv * wa.z; accM[3] += xv * wa.w;
            accM[4] += xv * wb.x; accM[5] += xv * wb.y;
            accM[6] += xv * wb.z; accM[7] += xv * wb.w;
        }
    }
    proj[v] = accP;
    float* ar = A + (size_t)v * RS;
    float4* a4 = reinterpret_cast<float4*>(ar);
    a4[0] = make_float4(accM[0], accM[1], accM[2], accM[3]);
    a4[1] = make_float4(accM[4], accM[5], accM[6], accM[7]);
}

// Per-edge argmax/argmin of proj over its K nodes (first occurrence wins),
// store Se/Ie, accumulate degree.
__global__ __launch_bounds__(256) void k_edge(const int* __restrict__ E,
                                              const float* __restrict__ proj,
                                              int* __restrict__ Se, int* __restrict__ Ie,
                                              float* __restrict__ deg) {
    int e = blockIdx.x * 256 + threadIdx.x;
    if (e >= NE) return;
    const int* er = E + (size_t)e * KE;
    int4 e0 = *reinterpret_cast<const int4*>(er);
    int4 e1 = *reinterpret_cast<const int4*>(er + 4);
    int ids[KE] = {e0.x, e0.y, e0.z, e0.w, e1.x, e1.y, e1.z, e1.w};
    float p0 = proj[ids[0]];
    float bestMax = p0, bestMin = p0;
    int idMax = ids[0], idMin = ids[0];
#pragma unroll
    for (int j = 1; j < KE; ++j) {
        float p = proj[ids[j]];
        if (p > bestMax) { bestMax = p; idMax = ids[j]; }
        if (p < bestMin) { bestMin = p; idMin = ids[j]; }
    }
    Se[e] = idMax;
    Ie[e] = idMin;
    atomicAdd(deg + idMax, 0.125f);
    atomicAdd(deg + idMin, 0.125f);
}

// dinv[v] = rsqrt(deg[v]); B[v,0:8] = dinv^2 * A[v,0:8]   (seed for spmm #1)
__global__ __launch_bounds__(256) void k_seed(const float* __restrict__ deg,
                                              float* __restrict__ dinv,
                                              const float* __restrict__ A,
                                              float* __restrict__ B) {
    int v = blockIdx.x * 256 + threadIdx.x;
    if (v >= VN) return;
    float di = rsqrtf(deg[v]);
    dinv[v] = di;
    float s = di * di;
    const float4* ar = reinterpret_cast<const float4*>(A + (size_t)v * RS);
    float4* br = reinterpret_cast<float4*>(B + (size_t)v * RS);
    float4 a0 = ar[0], a1 = ar[1];
    br[0] = make_float4(s * a0.x, s * a0.y, s * a0.z, s * a0.w);
    br[1] = make_float4(s * a1.x, s * a1.y, s * a1.z, s * a1.w);
}

// wv[e] = 0.125 * dinv[Se] * dinv[Ie]  (reused by all 3 spmm passes)
__global__ __launch_bounds__(256) void k_w(const int* __restrict__ Se,
                                           const int* __restrict__ Ie,
                                           const float* __restrict__ dinv,
                                           float* __restrict__ wv) {
    int e = blockIdx.x * 256 + threadIdx.x;
    if (e >= NE) return;
    wv[e] = 0.125f * dinv[Se[e]] * dinv[Ie[e]];
}

// Edge-parallel scatter: Y[s,:] += w*M[i,:]; Y[i,:] += w*M[s,:]
template <int F>
__global__ __launch_bounds__(256) void k_spmm(const int* __restrict__ Se,
                                              const int* __restrict__ Ie,
                                              const float* __restrict__ wv,
                                              const float* __restrict__ M,
                                              float* __restrict__ Y) {
    int e = blockIdx.x * 256 + threadIdx.x;
    if (e >= NE) return;
    int s = Se[e], i = Ie[e];
    float we = wv[e];
    const float* Ms = M + (size_t)s * RS;
    const float* Mi = M + (size_t)i * RS;
    float* Ys = Y + (size_t)s * RS;
    float* Yi = Y + (size_t)i * RS;
#pragma unroll
    for (int j = 0; j < F; ++j) {
        atomicAdd(&Ys[j], we * Mi[j]);
        atomicAdd(&Yi[j], we * Ms[j]);
    }
}

// H = relu(Y + bias); M_next = H @ W; A[v,:]=M_next; B[v,:]=dinv^2*M_next (seed)
template <int FIN, int FOUT>
__global__ __launch_bounds__(256) void k_layer(const float* __restrict__ bias,
                                               const float* __restrict__ W,
                                               const float* __restrict__ dinv,
                                               float* B,  // Y in / seed out (same rows)
                                               float* __restrict__ A) {
    int v = blockIdx.x * 256 + threadIdx.x;
    if (v >= VN) return;
    float h[FIN];
#pragma unroll
    for (int j = 0; j < FIN; ++j) {
        float y = B[(size_t)v * RS + j] + bias[j];
        h[j] = y > 0.f ? y : 0.f;
    }
    float di = dinv[v];
    float sc = di * di;
#pragma unroll
    for (int c = 0; c < FOUT; ++c) {
        float m = 0.f;
#pragma unroll
        for (int j = 0; j < FIN; ++j) m += h[j] * W[(size_t)j * FOUT + c];
        A[(size_t)v * RS + c] = m;
        B[(size_t)v * RS + c] = sc * m;
    }
}

// H = relu(Y3 + b3); logits = H@fc_w + fc_b; out = sigmoid(logits)
__global__ __launch_bounds__(256) void k_final(const float* __restrict__ b3,
                                               const float* __restrict__ fcw,
                                               const float* __restrict__ fcb,
                                               const float* __restrict__ B,
                                               float* __restrict__ out) {
    int v = blockIdx.x * 256 + threadIdx.x;
    if (v >= VN) return;
    float acc = fcb[0];
#pragma unroll
    for (int c = 0; c < CC; ++c) {
        float y = B[(size_t)v * RS + c] + b3[c];
        float hh = y > 0.f ? y : 0.f;
        acc += hh * fcw[c];
    }
    out[v] = 1.f / (1.f + expf(-acc));
}

extern "C" void kernel_launch(void* const* d_in, const int* in_sizes, int n_in,
                              void* d_out, int out_size, void* d_ws, size_t ws_size,
                              hipStream_t stream) {
    const float* X   = (const float*)d_in[0];
    const int*   E   = (const int*)d_in[1];
    const float* rv  = (const float*)d_in[2];
    const float* W1  = (const float*)d_in[3];
    const float* b1  = (const float*)d_in[4];
    const float* W2  = (const float*)d_in[5];
    const float* b2  = (const float*)d_in[6];
    const float* W3  = (const float*)d_in[7];
    const float* b3  = (const float*)d_in[8];
    const float* fcw = (const float*)d_in[9];
    const float* fcb = (const float*)d_in[10];
    float* out = (float*)d_out;

    float* ws   = (float*)d_ws;
    float* A    = ws;                 // [VN x 16]  M buffer
    float* B    = ws + 8000000;       // [VN x 16]  Y / seed buffer
    float* proj = ws + 16000000;      // [VN]
    float* deg  = ws + 16500000;      // [VN]
    float* dinv = ws + 17000000;      // [VN]
    float* wv   = ws + 17500000;      // [NE]
    int*   Se   = (int*)(ws + 18500000); // [NE]
    int*   Ie   = (int*)(ws + 19500000); // [NE]

    dim3 blk(256);
    int gV = (VN + 255) / 256;
    int gE = (NE + 255) / 256;

    k_init_deg<<<gV, blk, 0, stream>>>(deg);
    k_row<<<gV, blk, 0, stream>>>(X, rv, W1, proj, A);
    k_edge<<<gE, blk, 0, stream>>>(E, proj, Se, Ie, deg);
    k_seed<<<gV, blk, 0, stream>>>(deg, dinv, A, B);
    k_w<<<gE, blk, 0, stream>>>(Se, Ie, dinv, wv);

    // layer 1: Y1 = spmm(M1); H1 = relu(Y1+b1); M2 = H1@W2
    k_spmm<8><<<gE, blk, 0, stream>>>(Se, Ie, wv, A, B);
    k_layer<8, 8><<<gV, blk, 0, stream>>>(b1, W2, dinv, B, A);
    // layer 2: Y2 = spmm(M2); H2 = relu(Y2+b2); M3 = H2@W3
    k_spmm<8><<<gE, blk, 0, stream>>>(Se, Ie, wv, A, B);
    k_layer<8, 16><<<gV, blk, 0, stream>>>(b2, W3, dinv, B, A);
    // layer 3: Y3 = spmm(M3); out = sigmoid(relu(Y3+b3)@fc_w + fc_b)
    k_spmm<16><<<gE, blk, 0, stream>>>(Se, Ie, wv, A, B);
    k_final<<<gV, blk, 0, stream>>>(b3, fcw, fcb, B, out);
}

// Round 2
// 446.553 us; speedup vs baseline: 7.8850x; 7.8850x over previous
//
#include <hip/hip_runtime.h>
#include <hip/hip_bf16.h>

static constexpr int VN = 500000;   // nodes
static constexpr int DD = 128;      // feature dim
static constexpr int NE = 1000000;  // hyperedges
static constexpr int KE = 8;        // nodes per hyperedge
static constexpr int CC = 16;       // layer-3 width
static constexpr int H1 = 8;        // hidden width
static constexpr int RS = 16;       // row stride for A/B scratch
static constexpr int NB = (VN + 255) / 256;  // 1954 scan blocks

// zero the per-node incidence counters
__global__ __launch_bounds__(256) void k_zero(int* __restrict__ cnt) {
    int i = blockIdx.x * 256 + threadIdx.x;
    if (i < VN) cnt[i] = 0;
}

// Fused: proj[v] = X[v,:]·rv ; A[v,0:8] = X[v,:]·W1  (one pass over X)
__global__ __launch_bounds__(256) void k_row(const float* __restrict__ X,
                                             const float* __restrict__ rv,
                                             const float* __restrict__ W1,
                                             float* __restrict__ proj,
                                             float* __restrict__ A) {
    int v = blockIdx.x * 256 + threadIdx.x;
    if (v >= VN) return;
    const float4* xr = reinterpret_cast<const float4*>(X + (size_t)v * DD);
    const float4* rr = reinterpret_cast<const float4*>(rv);
    float accP = 0.f;
    float accM[H1];
#pragma unroll
    for (int j = 0; j < H1; ++j) accM[j] = 0.f;
#pragma unroll 8
    for (int k = 0; k < DD / 4; ++k) {
        float4 x = xr[k];
        float4 r = rr[k];
        accP += x.x * r.x + x.y * r.y + x.z * r.z + x.w * r.w;
#pragma unroll
        for (int q = 0; q < 4; ++q) {
            float xv = (q == 0) ? x.x : (q == 1) ? x.y : (q == 2) ? x.z : x.w;
            const float4 wa = *reinterpret_cast<const float4*>(W1 + (size_t)(k * 4 + q) * H1);
            const float4 wb = *reinterpret_cast<const float4*>(W1 + (size_t)(k * 4 + q) * H1 + 4);
            accM[0] += xv * wa.x; accM[1] += xv * wa.y;
            accM[2] += xv * wa.z; accM[3] += xv * wa.w;
            accM[4] += xv * wb.x; accM[5] += xv * wb.y;
            accM[6] += xv * wb.z; accM[7] += xv * wb.w;
        }
    }
    proj[v] = accP;
    float4* a4 = reinterpret_cast<float4*>(A + (size_t)v * RS);
    a4[0] = make_float4(accM[0], accM[1], accM[2], accM[3]);
    a4[1] = make_float4(accM[4], accM[5], accM[6], accM[7]);
}

// Per-edge argmax/argmin of proj (first occurrence wins); store Se/Ie;
// count incident entries per node (int atomics).
__global__ __launch_bounds__(256) void k_edge(const int* __restrict__ E,
                                              const float* __restrict__ proj,
                                              int* __restrict__ Se, int* __restrict__ Ie,
                                              int* __restrict__ cnt) {
    int e = blockIdx.x * 256 + threadIdx.x;
    if (e >= NE) return;
    const int* er = E + (size_t)e * KE;
    int4 e0 = *reinterpret_cast<const int4*>(er);
    int4 e1 = *reinterpret_cast<const int4*>(er + 4);
    int ids[KE] = {e0.x, e0.y, e0.z, e0.w, e1.x, e1.y, e1.z, e1.w};
    float p0 = proj[ids[0]];
    float bestMax = p0, bestMin = p0;
    int idMax = ids[0], idMin = ids[0];
#pragma unroll
    for (int j = 1; j < KE; ++j) {
        float p = proj[ids[j]];
        if (p > bestMax) { bestMax = p; idMax = ids[j]; }
        if (p < bestMin) { bestMin = p; idMin = ids[j]; }
    }
    Se[e] = idMax;
    Ie[e] = idMin;
    atomicAdd(cnt + idMax, 1);
    atomicAdd(cnt + idMin, 1);
}

// scan step 1: per-block sums of cnt
__global__ __launch_bounds__(256) void k_scan1(const int* __restrict__ cnt,
                                               int* __restrict__ bsum) {
    __shared__ int sm[256];
    int v = blockIdx.x * 256 + threadIdx.x;
    sm[threadIdx.x] = (v < VN) ? cnt[v] : 0;
    __syncthreads();
    for (int s = 128; s > 0; s >>= 1) {
        if (threadIdx.x < s) sm[threadIdx.x] += sm[threadIdx.x + s];
        __syncthreads();
    }
    if (threadIdx.x == 0) bsum[blockIdx.x] = sm[0];
}

// scan step 2: exclusive scan of block sums (single block, chunked)
__global__ __launch_bounds__(256) void k_scan2(int* __restrict__ bsum, int nb) {
    __shared__ int sm[256];
    __shared__ int carry;
    if (threadIdx.x == 0) carry = 0;
    __syncthreads();
    for (int base = 0; base < nb; base += 256) {
        int i = base + threadIdx.x;
        int x = (i < nb) ? bsum[i] : 0;
        sm[threadIdx.x] = x;
        __syncthreads();
        for (int off = 1; off < 256; off <<= 1) {
            int t = (threadIdx.x >= off) ? sm[threadIdx.x - off] : 0;
            __syncthreads();
            sm[threadIdx.x] += t;
            __syncthreads();
        }
        int excl = sm[threadIdx.x] - x;
        if (i < nb) bsum[i] = excl + carry;
        __syncthreads();
        if (threadIdx.x == 0) carry += sm[255];
        __syncthreads();
    }
}

// scan step 3: per-block exclusive scan + block offset -> rowptr; zero fill[]
__global__ __launch_bounds__(256) void k_scan3(const int* __restrict__ cnt,
                                               const int* __restrict__ bsum,
                                               int* __restrict__ rowptr,
                                               int* __restrict__ fill) {
    __shared__ int sm[256];
    int v = blockIdx.x * 256 + threadIdx.x;
    int x = (v < VN) ? cnt[v] : 0;
    sm[threadIdx.x] = x;
    __syncthreads();
    for (int off = 1; off < 256; off <<= 1) {
        int t = (threadIdx.x >= off) ? sm[threadIdx.x - off] : 0;
        __syncthreads();
        sm[threadIdx.x] += t;
        __syncthreads();
    }
    int excl = sm[threadIdx.x] - x + bsum[blockIdx.x];
    if (v < VN) { rowptr[v] = excl; fill[v] = 0; }
    if (v == VN - 1) rowptr[VN] = excl + x;
}

// fill CSR columns (slot via atomic)
__global__ __launch_bounds__(256) void k_fill(const int* __restrict__ Se,
                                              const int* __restrict__ Ie,
                                              const int* __restrict__ rowptr,
                                              int* __restrict__ fill,
                                              int* __restrict__ colv) {
    int e = blockIdx.x * 256 + threadIdx.x;
    if (e >= NE) return;
    int s = Se[e], i = Ie[e];
    int ps = atomicAdd(fill + s, 1);
    colv[rowptr[s] + ps] = i;
    int pi = atomicAdd(fill + i, 1);
    colv[rowptr[i] + pi] = s;
}

// dinv[v] = rsqrt(1 + cnt/8); scale A in place: A = dinv * M1  (M')
__global__ __launch_bounds__(256) void k_seed(const int* __restrict__ cnt,
                                              float* __restrict__ dinv,
                                              float* __restrict__ A) {
    int v = blockIdx.x * 256 + threadIdx.x;
    if (v >= VN) return;
    float di = rsqrtf(1.0f + 0.125f * (float)cnt[v]);
    dinv[v] = di;
    float4* ar = reinterpret_cast<float4*>(A + (size_t)v * RS);
    float4 a0 = ar[0], a1 = ar[1];
    ar[0] = make_float4(di * a0.x, di * a0.y, di * a0.z, di * a0.w);
    ar[1] = make_float4(di * a1.x, di * a1.y, di * a1.z, di * a1.w);
}

// Gather SpMM + bias + ReLU + tiny matmul, writes next M' = dinv*(H@W).
// Y[v] = dinv[v]*(M'[v] + 0.125*sum_c M'[c])
template <int FIN, int FOUT>
__global__ __launch_bounds__(256) void k_glayer(const int* __restrict__ rowptr,
                                                const int* __restrict__ colv,
                                                const float* __restrict__ dinv,
                                                const float* __restrict__ bias,
                                                const float* __restrict__ W,
                                                const float* __restrict__ Min,
                                                float* __restrict__ Mout) {
    int v = blockIdx.x * 256 + threadIdx.x;
    if (v >= VN) return;
    float own[FIN], s[FIN];
    const float4* mr = reinterpret_cast<const float4*>(Min + (size_t)v * RS);
#pragma unroll
    for (int j = 0; j < FIN / 4; ++j) {
        float4 t = mr[j];
        own[4 * j] = t.x; own[4 * j + 1] = t.y;
        own[4 * j + 2] = t.z; own[4 * j + 3] = t.w;
    }
#pragma unroll
    for (int j = 0; j < FIN; ++j) s[j] = 0.f;
    int beg = rowptr[v], end = rowptr[v + 1];
    for (int p = beg; p < end; ++p) {
        int c = colv[p];
        const float4* cr = reinterpret_cast<const float4*>(Min + (size_t)c * RS);
#pragma unroll
        for (int j = 0; j < FIN / 4; ++j) {
            float4 t = cr[j];
            s[4 * j] += t.x; s[4 * j + 1] += t.y;
            s[4 * j + 2] += t.z; s[4 * j + 3] += t.w;
        }
    }
    float di = dinv[v];
    float h[FIN];
#pragma unroll
    for (int j = 0; j < FIN; ++j) {
        float y = di * (own[j] + 0.125f * s[j]) + bias[j];
        h[j] = y > 0.f ? y : 0.f;
    }
#pragma unroll
    for (int c = 0; c < FOUT; ++c) {
        float m = 0.f;
#pragma unroll
        for (int j = 0; j < FIN; ++j) m += h[j] * W[j * FOUT + c];
        Mout[(size_t)v * RS + c] = di * m;
    }
}

// Final: gather Y3, relu(Y3+b3), dot with fc_w, sigmoid
__global__ __launch_bounds__(256) void k_gfinal(const int* __restrict__ rowptr,
                                                const int* __restrict__ colv,
                                                const float* __restrict__ dinv,
                                                const float* __restrict__ b3,
                                                const float* __restrict__ fcw,
                                                const float* __restrict__ fcb,
                                                const float* __restrict__ Min,
                                                float* __restrict__ out) {
    int v = blockIdx.x * 256 + threadIdx.x;
    if (v >= VN) return;
    float own[CC], s[CC];
    const float4* mr = reinterpret_cast<const float4*>(Min + (size_t)v * RS);
#pragma unroll
    for (int j = 0; j < CC / 4; ++j) {
        float4 t = mr[j];
        own[4 * j] = t.x; own[4 * j + 1] = t.y;
        own[4 * j + 2] = t.z; own[4 * j + 3] = t.w;
    }
#pragma unroll
    for (int j = 0; j < CC; ++j) s[j] = 0.f;
    int beg = rowptr[v], end = rowptr[v + 1];
    for (int p = beg; p < end; ++p) {
        int c = colv[p];
        const float4* cr = reinterpret_cast<const float4*>(Min + (size_t)c * RS);
#pragma unroll
        for (int j = 0; j < CC / 4; ++j) {
            float4 t = cr[j];
            s[4 * j] += t.x; s[4 * j + 1] += t.y;
            s[4 * j + 2] += t.z; s[4 * j + 3] += t.w;
        }
    }
    float di = dinv[v];
    float acc = fcb[0];
#pragma unroll
    for (int j = 0; j < CC; ++j) {
        float y = di * (own[j] + 0.125f * s[j]) + b3[j];
        float hh = y > 0.f ? y : 0.f;
        acc += hh * fcw[j];
    }
    out[v] = 1.f / (1.f + expf(-acc));
}

extern "C" void kernel_launch(void* const* d_in, const int* in_sizes, int n_in,
                              void* d_out, int out_size, void* d_ws, size_t ws_size,
                              hipStream_t stream) {
    const float* X   = (const float*)d_in[0];
    const int*   E   = (const int*)d_in[1];
    const float* rv  = (const float*)d_in[2];
    const float* W1  = (const float*)d_in[3];
    const float* b1  = (const float*)d_in[4];
    const float* W2  = (const float*)d_in[5];
    const float* b2  = (const float*)d_in[6];
    const float* W3  = (const float*)d_in[7];
    const float* b3  = (const float*)d_in[8];
    const float* fcw = (const float*)d_in[9];
    const float* fcb = (const float*)d_in[10];
    float* out = (float*)d_out;

    float* ws   = (float*)d_ws;
    float* A    = ws;                        // [VN x 16] M' buffer (ping)
    float* B    = ws + 8000000;              // [VN x 16] M' buffer (pong)
    int*   Se   = (int*)(ws + 8000000);      // overlay B: dead before B written
    int*   Ie   = (int*)(ws + 9000000);      // overlay B
    float* proj = ws + 16000000;             // [VN]
    float* dinv = ws + 16500000;             // [VN]
    int*   cnt  = (int*)(ws + 17000000);     // [VN]
    int*   rowptr = (int*)(ws + 17500000);   // [VN+1]
    int*   fill = (int*)(ws + 18001000);     // [VN]
    int*   bsum = (int*)(ws + 18501000);     // [NB]
    int*   colv = (int*)(ws + 18504000);     // [2*NE]

    dim3 blk(256);
    int gV = (VN + 255) / 256;   // = NB
    int gE = (NE + 255) / 256;

    k_zero<<<gV, blk, 0, stream>>>(cnt);
    k_row<<<gV, blk, 0, stream>>>(X, rv, W1, proj, A);
    k_edge<<<gE, blk, 0, stream>>>(E, proj, Se, Ie, cnt);
    k_scan1<<<gV, blk, 0, stream>>>(cnt, bsum);
    k_scan2<<<1, blk, 0, stream>>>(bsum, NB);
    k_scan3<<<gV, blk, 0, stream>>>(cnt, bsum, rowptr, fill);
    k_fill<<<gE, blk, 0, stream>>>(Se, Ie, rowptr, fill, colv);
    k_seed<<<gV, blk, 0, stream>>>(cnt, dinv, A);

    // layer 1: A(M1') -> B(M2')
    k_glayer<8, 8><<<gV, blk, 0, stream>>>(rowptr, colv, dinv, b1, W2, A, B);
    // layer 2: B(M2') -> A(M3')
    k_glayer<8, 16><<<gV, blk, 0, stream>>>(rowptr, colv, dinv, b2, W3, B, A);
    // layer 3 + head: A(M3') -> out
    k_gfinal<<<gV, blk, 0, stream>>>(rowptr, colv, dinv, b3, fcw, fcb, A, out);
}